// Round 25
// baseline (264.503 us; speedup 1.0000x reference)
//
#include <hip/hip_runtime.h>
#include <hip/hip_bf16.h>
#include <math.h>
#include <stdint.h>

// ---- problem constants ----
static constexpr int B_    = 2;
static constexpr int N_    = 12544;   // 112*112
static constexpr int DIM_  = 512;
static constexpr int D0_   = 64;
static constexpr int DL_   = 448;
static constexpr int Himg  = 112;
static constexpr int Wimg  = 112;
static constexpr int HS_   = 56;
static constexpr int NR_   = 3136;    // 56*56
static constexpr int NH_   = 8;
static constexpr int HD_   = 28;
static constexpr int NSPLIT = 8;

typedef unsigned short ushort_t;
typedef __attribute__((ext_vector_type(8))) short short8_t;
typedef __attribute__((ext_vector_type(4))) float float4v;
typedef __attribute__((ext_vector_type(4))) unsigned uint4v;
typedef __attribute__((ext_vector_type(2))) unsigned uint2v;

static __device__ inline ushort_t bf16r(float x) {
    unsigned u = __builtin_bit_cast(unsigned, x);
    u = (u + 0x7FFFu + ((u >> 16) & 1u)) >> 16;
    return (ushort_t)u;
}
static __device__ inline float bf16tof(ushort_t h) {
    unsigned u = ((unsigned)h) << 16;
    return __builtin_bit_cast(float, u);
}
static __device__ inline unsigned pack_bf16(float lo, float hi) {
    unsigned a = __builtin_bit_cast(unsigned, lo);
    unsigned b = __builtin_bit_cast(unsigned, hi);
    a = (a + 0x7FFFu + ((a >> 16) & 1u)) >> 16;
    b = (b + 0x7FFFu + ((b >> 16) & 1u)) >> 16;
    return a | (b << 16);
}
static __device__ inline unsigned cvtpk(float lo, float hi) {
    float2 f2; f2.x = lo; f2.y = hi;
    __hip_bfloat162 h = __float22bfloat162_rn(f2);
    unsigned u;
    __builtin_memcpy(&u, &h, 4);
    return u;
}

using gptr_t = const __attribute__((address_space(1))) void*;
using lptr_t = __attribute__((address_space(3))) void*;
static __device__ inline void gload16(const void* g, void* l) {
    __builtin_amdgcn_global_load_lds((gptr_t)(uintptr_t)g, (lptr_t)(uintptr_t)l, 16, 0, 0);
}

// =====================================================================
// Double-buffered GEMM K-loop core (T3/T4 minimum 2-phase):
// issue stage(t+1) BEFORE compute(t); counted vmcnt(8) keeps the 8
// prefetch loads in flight across RAW s_barrier (no compiler drain).
// smem layout: [0,16K) As0 | [16K,32K) Bs0 | [32K,48K) As1 | [48K,64K) Bs1
// =====================================================================
static __device__ inline void gemm_core_dbuf(const ushort_t* __restrict__ A,
                                             const ushort_t* __restrict__ Bt,
                                             int K, int bm, int bn, char* smem,
                                             int tid, float4v acc[4][4]) {
    ushort_t* As0 = (ushort_t*)smem;
    ushort_t* Bs0 = (ushort_t*)(smem + 16384);
    ushort_t* As1 = (ushort_t*)(smem + 32768);
    ushort_t* Bs1 = (ushort_t*)(smem + 49152);
    const int l15 = tid & 15;
    const int g   = (tid & 63) >> 4;
    const int w   = tid >> 6;
    const int wr  = w >> 1, wc = w & 1;

    auto stageT = [&](int k0, int buf) {
        ushort_t* Ad = buf ? As1 : As0;
        ushort_t* Bd = buf ? Bs1 : Bs0;
        #pragma unroll
        for (int i = 0; i < 4; ++i) {
            int c = i * 256 + tid;
            int r = c >> 3, ch = c & 7;
            int sch = ch ^ (r & 7);
            gload16(A  + (size_t)(bm + r) * K + k0 + sch * 8, (void*)(Ad + c * 8));
            gload16(Bt + (size_t)(bn + r) * K + k0 + sch * 8, (void*)(Bd + c * 8));
        }
    };

    const int nt = K >> 6;
    stageT(0, 0);
    for (int t = 0; t < nt; ++t) {
        const int buf = t & 1;
        if (t + 1 < nt) {
            stageT((t + 1) << 6, buf ^ 1);
            asm volatile("s_waitcnt vmcnt(8)" ::: "memory");   // tile t done; t+1 in flight
        } else {
            asm volatile("s_waitcnt vmcnt(0)" ::: "memory");   // final tile: full drain
        }
        __builtin_amdgcn_sched_barrier(0);
        __builtin_amdgcn_s_barrier();

        const char* Asb = (const char*)(buf ? As1 : As0);
        const char* Bsb = (const char*)(buf ? Bs1 : Bs0);
        short8_t af[4][2], bfr[4][2];
        #pragma unroll
        for (int m = 0; m < 4; ++m) {
            int ar = wr * 64 + m * 16 + l15;
            #pragma unroll
            for (int h = 0; h < 2; ++h)
                af[m][h] = *(const short8_t*)(Asb + ar * 128 + (((h * 4 + g) ^ (ar & 7)) * 16));
        }
        #pragma unroll
        for (int n = 0; n < 4; ++n) {
            int br = wc * 64 + n * 16 + l15;
            #pragma unroll
            for (int h = 0; h < 2; ++h)
                bfr[n][h] = *(const short8_t*)(Bsb + br * 128 + (((h * 4 + g) ^ (br & 7)) * 16));
        }
        #pragma unroll
        for (int m = 0; m < 4; ++m)
            #pragma unroll
            for (int n = 0; n < 4; ++n) {
                acc[m][n] = __builtin_amdgcn_mfma_f32_16x16x32_bf16(af[m][0], bfr[n][0], acc[m][n], 0, 0, 0);
                acc[m][n] = __builtin_amdgcn_mfma_f32_16x16x32_bf16(af[m][1], bfr[n][1], acc[m][n], 0, 0, 0);
            }
        asm volatile("s_waitcnt lgkmcnt(0)" ::: "memory");     // ds_reads retired
        __builtin_amdgcn_s_barrier();                          // safe to overwrite buf
    }
}

// =====================================================================
// bf16 MFMA GEMM (standalone, used for proj only) — dbuf core
// =====================================================================
template<bool HASBIAS, bool OUT16>
__global__ __launch_bounds__(256, 2)
void gemm_bf16_kernel(const ushort_t* __restrict__ A,
                      const ushort_t* __restrict__ Bt,
                      const float* __restrict__ bias,
                      void* __restrict__ Cv,
                      int Nn, int K, int ldc) {
    __shared__ __align__(16) char smem[65536];
    const int bm = blockIdx.x * 128;
    const int bn = blockIdx.y * 128;
    const int tid = threadIdx.x;
    const int l15 = tid & 15;
    const int g   = (tid & 63) >> 4;
    const int w   = tid >> 6;
    const int wr  = w >> 1, wc = w & 1;

    float4v acc[4][4];
    #pragma unroll
    for (int m = 0; m < 4; ++m)
        #pragma unroll
        for (int n = 0; n < 4; ++n) acc[m][n] = (float4v){0.f, 0.f, 0.f, 0.f};

    gemm_core_dbuf(A, Bt, K, bm, bn, smem, tid, acc);

    #pragma unroll
    for (int n = 0; n < 4; ++n) {
        int ccol = bn + wc * 64 + n * 16 + l15;
        if (ccol < Nn) {
            float bv = HASBIAS ? bias[ccol] : 0.f;
            #pragma unroll
            for (int m = 0; m < 4; ++m) {
                int crow = bm + wr * 64 + m * 16 + g * 4;
                #pragma unroll
                for (int j = 0; j < 4; ++j) {
                    float v = acc[m][n][j] + bv;
                    if (OUT16)
                        ((ushort_t*)Cv)[(size_t)(crow + j) * ldc + ccol] = bf16r(v);
                    else
                        ((float*)Cv)[(size_t)(crow + j) * ldc + ccol] = v;
                }
            }
        }
    }
}

// =====================================================================
// merged prep: wqt, pwt, projt, srwt, xbf
// =====================================================================
__global__ __launch_bounds__(256)
void prep_kernel(const float* __restrict__ Wq, const float* __restrict__ kvl_pw,
                 const float* __restrict__ proj_w, const float* __restrict__ sr_w,
                 const float* __restrict__ x,
                 ushort_t* __restrict__ wqt, ushort_t* __restrict__ pwt,
                 ushort_t* __restrict__ projt, float* __restrict__ srwt,
                 ushort_t* __restrict__ xbf) {
    int idx = blockIdx.x * 256 + threadIdx.x;
    if (idx < 262144) {
        int n = idx >> 9, k = idx & 511;
        wqt[idx] = bf16r(Wq[(size_t)k * 512 + n]);
    } else if (idx < 491520) {
        int i = idx - 262144;
        int n = i / 448, k = i % 448;
        float v = (n < 448) ? kvl_pw[(size_t)n * 448 + k] : 0.f;
        pwt[i] = bf16r(v);
    } else if (idx < 753664) {
        int i = idx - 491520;
        int n = i >> 9, k = i & 511;
        projt[i] = bf16r(proj_w[(size_t)k * 512 + n]);
    } else if (idx < 770048) {
        int i = idx - 753664;
        int f = i >> 6, o2 = i & 63;
        srwt[i] = sr_w[o2 * 256 + f];
    } else {
        int i = idx - 770048;
        const float4v* p = (const float4v*)(x + (size_t)i * 8);
        float4v a = p[0], b = p[1];
        uint4v u;
        u[0] = pack_bf16(a[0], a[1]);
        u[1] = pack_bf16(a[2], a[3]);
        u[2] = pack_bf16(b[0], b[1]);
        u[3] = pack_bf16(b[2], b[3]);
        *(uint4v*)(xbf + (size_t)i * 8) = u;
    }
}

// =====================================================================
// FUSED3: [0,784) q-GEMM (dbuf) | [784,3528) dwt | [3528,5096) srlnkv x4
// single 64KB LDS union across branches
// =====================================================================
__global__ __launch_bounds__(256, 2)
void fused3_kernel(const ushort_t* __restrict__ xbf, const ushort_t* __restrict__ wqt,
                   ushort_t* __restrict__ q16,
                   const float* __restrict__ kvl_dw, const float* __restrict__ kvl_db,
                   ushort_t* __restrict__ dwtb,
                   const float* __restrict__ x, const float* __restrict__ srwt,
                   const float* __restrict__ sr_b, const float* __restrict__ ln_g,
                   const float* __restrict__ ln_b, const float* __restrict__ wkv,
                   ushort_t* __restrict__ kgb, float* __restrict__ vg) {
    const int bid = blockIdx.x;
    const int tid = threadIdx.x;
    __shared__ __align__(16) char smem[65536];

    if (bid < 784) {
        const int bm = (bid % 196) * 128;
        const int bn = (bid / 196) * 128;
        const int l15 = tid & 15;
        const int g   = (tid & 63) >> 4;
        const int w   = tid >> 6;
        const int wr  = w >> 1, wc = w & 1;
        float4v acc[4][4];
        #pragma unroll
        for (int m = 0; m < 4; ++m)
            #pragma unroll
            for (int n = 0; n < 4; ++n) acc[m][n] = (float4v){0.f, 0.f, 0.f, 0.f};

        gemm_core_dbuf(xbf, wqt, 512, bm, bn, smem, tid, acc);

        #pragma unroll
        for (int n = 0; n < 4; ++n) {
            int ccol = bn + wc * 64 + n * 16 + l15;
            #pragma unroll
            for (int m = 0; m < 4; ++m) {
                int crow = bm + wr * 64 + m * 16 + g * 4;
                #pragma unroll
                for (int j = 0; j < 4; ++j)
                    q16[(size_t)(crow + j) * 512 + ccol] = bf16r(acc[m][n][j]);
            }
        }
    } else if (bid < 3528) {
        int idx = (bid - 784) * 256 + tid;
        int c4 = idx % 112;
        int t1 = idx / 112;
        int xx = t1 % 112;
        int t2 = t1 / 112;
        int yg = t2 % 28;
        int b  = t2 / 28;
        int c0 = c4 * 4;
        int y0 = yg * 4;
        float4v w4[9];
        #pragma unroll
        for (int kt = 0; kt < 9; ++kt) {
            w4[kt][0] = kvl_dw[(c0 + 0) * 9 + kt];
            w4[kt][1] = kvl_dw[(c0 + 1) * 9 + kt];
            w4[kt][2] = kvl_dw[(c0 + 2) * 9 + kt];
            w4[kt][3] = kvl_dw[(c0 + 3) * 9 + kt];
        }
        float4v bv = *(const float4v*)(kvl_db + c0);
        float4v acc[4];
        #pragma unroll
        for (int o2 = 0; o2 < 4; ++o2) acc[o2] = bv;
        #pragma unroll
        for (int yy = 0; yy < 6; ++yy) {
            int Y = y0 - 1 + yy;
            if (Y < 0 || Y >= Himg) continue;
            #pragma unroll
            for (int xt = 0; xt < 3; ++xt) {
                int X = xx - 1 + xt;
                if (X < 0 || X >= Wimg) continue;
                uint2v q2 = *(const uint2v*)(xbf + ((size_t)b * N_ + Y * Wimg + X) * DIM_ + D0_ + c0);
                float4v v;
                v[0] = bf16tof((ushort_t)(q2[0] & 0xffffu));
                v[1] = bf16tof((ushort_t)(q2[0] >> 16));
                v[2] = bf16tof((ushort_t)(q2[1] & 0xffffu));
                v[3] = bf16tof((ushort_t)(q2[1] >> 16));
                constexpr int olo_t[6] = {0, 0, 0, 1, 2, 3};
                constexpr int ohi_t[6] = {0, 1, 2, 3, 3, 3};
                #pragma unroll
                for (int o2 = olo_t[yy]; o2 <= ohi_t[yy]; ++o2) {
                    float4v wv = w4[(yy - o2) * 3 + xt];
                    acc[o2][0] += v[0] * wv[0];
                    acc[o2][1] += v[1] * wv[1];
                    acc[o2][2] += v[2] * wv[2];
                    acc[o2][3] += v[3] * wv[3];
                }
            }
        }
        #pragma unroll
        for (int o2 = 0; o2 < 4; ++o2) {
            uint2v pk;
            pk[0] = pack_bf16(acc[o2][0], acc[o2][1]);
            pk[1] = pack_bf16(acc[o2][2], acc[o2][3]);
            *(uint2v*)(dwtb + ((size_t)b * N_ + (y0 + o2) * Wimg + xx) * DL_ + c0) = pk;
        }
    } else {
        // srlnkv: 4 positions per block; LDS overlays smem (first 5KB)
        float* xs    = (float*)smem;            // [grp*256 + tap*64 + o], 4KB
        float* lnv_s = (float*)(smem + 4096);   // [grp*64 + o], 1KB
        const int blk4 = bid - 3528;
        const int grp  = tid >> 6;
        const int o    = tid & 63;
        const int pos  = blk4 * 4 + grp;
        const int b = pos / NR_, n = pos % NR_;
        const int y = n / HS_, xx = n % HS_;
        #pragma unroll
        for (int tap = 0; tap < 4; ++tap) {
            int ky = tap / 2, kx = tap % 2;
            xs[grp * 256 + tap * 64 + o] =
                x[((size_t)b * N_ + (2 * y + ky) * Wimg + 2 * xx + kx) * DIM_ + o];
        }
        __syncthreads();
        float sum = sr_b[o];
        for (int i = 0; i < 64; ++i) {
            const float* wr = srwt + (i * 4) * 64 + o;
            sum += xs[grp * 256 + 0 * 64 + i] * wr[0] + xs[grp * 256 + 1 * 64 + i] * wr[64]
                 + xs[grp * 256 + 2 * 64 + i] * wr[128] + xs[grp * 256 + 3 * 64 + i] * wr[192];
        }
        float m = sum;
        #pragma unroll
        for (int off = 1; off < 64; off <<= 1) m += __shfl_xor(m, off);
        m *= (1.0f / 64.0f);
        float d = sum - m;
        float v = d * d;
        #pragma unroll
        for (int off = 1; off < 64; off <<= 1) v += __shfl_xor(v, off);
        v *= (1.0f / 64.0f);
        float lnv = d * rsqrtf(v + 1e-5f) * ln_g[o] + ln_b[o];
        lnv_s[grp * 64 + o] = lnv;
        __syncthreads();
        float s0 = 0.f, s1 = 0.f;
        for (int i = 0; i < 64; ++i) {
            float lv = lnv_s[grp * 64 + i];
            s0 += lv * wkv[i * 128 + o];
            s1 += lv * wkv[i * 128 + o + 64];
        }
        const float SCK = 0.125f * 1.44269504088896340736f;
        kgb[((size_t)b * NR_ + n) * 64 + o] = bf16r(s0 * SCK);
        vg[((size_t)b * NR_ + n) * 64 + o] = s1;
    }
}

// =====================================================================
// FUSED2: [0,784) pointwise GEMM (dbuf) -> kvl16 | [784,882) lcg+vtrans
// single 64KB LDS union
// =====================================================================
__global__ __launch_bounds__(256, 2)
void fused2_kernel(const ushort_t* __restrict__ dwtb, const ushort_t* __restrict__ pwt,
                   const float* __restrict__ kvl_pb, ushort_t* __restrict__ kvl16,
                   const float* __restrict__ vg, const float* __restrict__ lcg_w,
                   const float* __restrict__ lcg_b, ushort_t* __restrict__ vtb) {
    const int bid = blockIdx.x;
    const int tid = threadIdx.x;
    __shared__ __align__(16) char smem[65536];

    if (bid < 784) {
        const int bm = (bid % 196) * 128;
        const int bn = (bid / 196) * 128;
        const int l15 = tid & 15;
        const int g   = (tid & 63) >> 4;
        const int w   = tid >> 6;
        const int wr  = w >> 1, wc = w & 1;
        float4v acc[4][4];
        #pragma unroll
        for (int m = 0; m < 4; ++m)
            #pragma unroll
            for (int n = 0; n < 4; ++n) acc[m][n] = (float4v){0.f, 0.f, 0.f, 0.f};

        gemm_core_dbuf(dwtb, pwt, 448, bm, bn, smem, tid, acc);

        #pragma unroll
        for (int n = 0; n < 4; ++n) {
            int ccol = bn + wc * 64 + n * 16 + l15;
            if (ccol < 448) {
                float bv = kvl_pb[ccol];
                #pragma unroll
                for (int m = 0; m < 4; ++m) {
                    int crow = bm + wr * 64 + m * 16 + g * 4;
                    #pragma unroll
                    for (int j = 0; j < 4; ++j)
                        kvl16[(size_t)(crow + j) * 448 + ccol] = bf16r(acc[m][n][j] + bv);
                }
            }
        }
    } else {
        float* ld = (float*)smem;   // [n*65 + c], 64*65*4 = 16.6KB
        const int lb = bid - 784;
        const int b = lb / 49, n0 = (lb % 49) * 64;
        #pragma unroll
        for (int i = 0; i < 16; ++i) {
            int idx = i * 256 + tid;
            int n = idx >> 6, c = idx & 63;
            int nn = n0 + n;
            int y = nn / HS_, xx = nn % HS_;
            float sum = vg[((size_t)b * NR_ + nn) * 64 + c] + lcg_b[c];
            #pragma unroll
            for (int ky = 0; ky < 3; ++ky)
                #pragma unroll
                for (int kx = 0; kx < 3; ++kx) {
                    int yy = y + ky - 1, x2 = xx + kx - 1;
                    if (yy >= 0 && yy < HS_ && x2 >= 0 && x2 < HS_)
                        sum += vg[((size_t)b * NR_ + yy * HS_ + x2) * 64 + c] * lcg_w[c * 9 + ky * 3 + kx];
                }
            ld[n * 65 + c] = sum;
        }
        __syncthreads();
        #pragma unroll
        for (int i = 0; i < 16; ++i) {
            int idx = i * 256 + tid;
            int d = idx >> 6, nn = idx & 63;
            vtb[(size_t)(b * 64 + d) * NR_ + n0 + nn] = bf16r(ld[nn * 65 + d]);
        }
    }
}

// =====================================================================
// "scrambled mean" body (bf16 kvl), shared mem passed in
// =====================================================================
template<int L, int NBW, int STRIDE, int DIL, int CHOFF>
__device__ inline void lm_body(int blk, int t, float* slo, float* shi,
                               const ushort_t* __restrict__ kvl16,
                               float* __restrict__ kvm) {
    const int n = blk % 49;
    const int h = (blk / 49) % NH_;
    const int b = blk / (49 * NH_);
    const int wy = n / 7, wx = n % 7;

    if (t < L) {
        const int by = t / NBW, bx = t % NBW;
        int Y = by * STRIDE + DIL * wy;
        int X = bx * STRIDE + DIL * wx;
        if (Y >= Himg) Y = 2 * Himg - 2 - Y;
        if (X >= Wimg) X = 2 * Wimg - 2 - X;
        const ushort_t* src = kvl16 + ((size_t)b * N_ + Y * Wimg + X) * DL_ + CHOFF + h * HD_;
        float v[28];
        #pragma unroll
        for (int i = 0; i < 7; ++i) {
            uint2v q2 = ((const uint2v*)src)[i];
            v[i * 4]     = bf16tof((ushort_t)(q2[0] & 0xffffu));
            v[i * 4 + 1] = bf16tof((ushort_t)(q2[0] >> 16));
            v[i * 4 + 2] = bf16tof((ushort_t)(q2[1] & 0xffffu));
            v[i * 4 + 3] = bf16tof((ushort_t)(q2[1] >> 16));
        }
        const int f0 = t * HD_;
        const int bin0 = f0 / L;
        const int nlo = min(HD_, (bin0 + 1) * L - f0);
        float s0 = 0.f, s1 = 0.f;
        #pragma unroll
        for (int j = 0; j < HD_; ++j) {
            if (j < nlo) s0 += v[j]; else s1 += v[j];
        }
        slo[t] = s0;
        shi[t] = s1;
    }
    __syncthreads();
    if (t < HD_) {
        const int t_lo = (t * L) / HD_;
        const int t_hi = min(L - 1, (t * L + L - 1) / HD_);
        float sum = 0.f;
        for (int u = t_lo; u <= t_hi; ++u) {
            int f0 = u * HD_;
            int b0 = f0 / L;
            int b1 = (f0 + HD_ - 1) / L;
            if (b0 == t) sum += slo[u];
            if (b1 == t && b1 != b0) sum += shi[u];
        }
        kvm[(size_t)blk * HD_ + t] = sum * (1.0f / (float)L);
    }
}

// =====================================================================
// FUSED attn_global + local_mean (32KB LDS union)
// [0,1568): attn_global (512 thr); [1568,3136): lm
// =====================================================================
__global__ __launch_bounds__(512)
void fused_ag_lm_kernel(const ushort_t* __restrict__ q16,
                        const ushort_t* __restrict__ kgb,
                        const ushort_t* __restrict__ vtb,
                        ushort_t* __restrict__ osp16, float* __restrict__ mls,
                        const ushort_t* __restrict__ kvl16,
                        float* __restrict__ kvm1, float* __restrict__ kvm2) {
    const int bid = blockIdx.x;
    const int tid = threadIdx.x;
    __shared__ __align__(16) char smem[32768];
    ushort_t* Ks = (ushort_t*)smem;
    ushort_t* Vs = (ushort_t*)(smem + 16384);

    if (bid >= 1568) {
        float* slo = (float*)smem;            // up to 256 floats
        float* shi = (float*)(smem + 1024);
        int lmid = bid - 1568;
        int blk = lmid % 784;
        if (lmid < 784) lm_body<256, 16, 7, 1, 0>(blk, tid, slo, shi, kvl16, kvm1);
        else            lm_body<81, 9, 13, 2, 224>(blk, tid, slo, shi, kvl16, kvm2);
        return;
    }

    const int split = (bid / 98) & 7;
    const int b     = (bid / 98) >> 3;
    const int q0    = (bid % 98) * 128;
    const int w     = tid >> 6;
    const int l     = tid & 63;
    const int l15   = l & 15;
    const int g     = l >> 4;
    const int lx    = l15 & 7;

    short8_t qf[2];
    {
        const ushort_t* qrow = q16 + ((size_t)b * N_ + q0 + w * 16 + l15) * DIM_;
        qf[0] = *(const short8_t*)(qrow + g * 8);
        qf[1] = *(const short8_t*)(qrow + g * 8 + 32);
    }

    float4v o[4];
    #pragma unroll
    for (int i = 0; i < 4; ++i) o[i] = (float4v){0.f, 0.f, 0.f, 0.f};
    float m_run = -3.0e38f, l_run = 0.f;

    const int stg_r   = tid >> 3;
    const int stg_sch = (tid & 7) ^ (stg_r & 7);
    const int stg_pr  = (stg_r & 32) | (((stg_r >> 2) & 3) << 3) | (((stg_r >> 4) & 1) << 2) | (stg_r & 3);
    auto stage = [&](int t, int buf) {
        const int k0 = t * 64;
        gload16(kgb + ((size_t)(b * NR_ + k0 + stg_pr) << 6) + stg_sch * 8,
                (void*)(Ks + buf * 4096 + tid * 8));
        gload16(vtb + (size_t)(b * 64 + stg_r) * NR_ + k0 + stg_sch * 8,
                (void*)(Vs + buf * 4096 + tid * 8));
    };

    auto compute = [&](const ushort_t* Kb, const ushort_t* Vb) {
        float4v sc[4];
        #pragma unroll
        for (int c = 0; c < 4; ++c) {
            float4v acc = (float4v){0.f, 0.f, 0.f, 0.f};
            #pragma unroll
            for (int dc = 0; dc < 2; ++dc) {
                int row = c * 16 + l15;
                short8_t ak = *(const short8_t*)((const char*)Kb + row * 128 + (((g + 4 * dc) ^ lx) * 16));
                acc = __builtin_amdgcn_mfma_f32_16x16x32_bf16(ak, qf[dc], acc, 0, 0, 0);
            }
            sc[c] = acc;
        }

        float tmax = fmaxf(fmaxf(fmaxf(sc[0][0], sc[0][1]), fmaxf(sc[0][2], sc[0][3])),
                           fmaxf(fmaxf(sc[1][0], sc[1][1]), fmaxf(sc[1][2], sc[1][3])));
        tmax = fmaxf(tmax, fmaxf(fmaxf(fmaxf(sc[2][0], sc[2][1]), fmaxf(sc[2][2], sc[2][3])),
                                 fmaxf(fmaxf(sc[3][0], sc[3][1]), fmaxf(sc[3][2], sc[3][3]))));

        if (__any(tmax > m_run + 11.0f)) {
            float rmax = fmaxf(tmax, __shfl_xor(tmax, 16));
            rmax = fmaxf(rmax, __shfl_xor(rmax, 32));
            float m_new = fmaxf(m_run, rmax);
            float corr = __builtin_amdgcn_exp2f(m_run - m_new);
            float co[4];
            #pragma unroll
            for (int r = 0; r < 4; ++r) co[r] = __shfl(corr, g * 4 + r);
            #pragma unroll
            for (int dc = 0; dc < 4; ++dc)
                #pragma unroll
                for (int r = 0; r < 4; ++r) o[dc][r] *= co[r];
            l_run *= corr;
            m_run = m_new;
        }

        float p[4][4];
        float ladd = 0.f;
        #pragma unroll
        for (int c = 0; c < 4; ++c)
            #pragma unroll
            for (int r = 0; r < 4; ++r) {
                float pe = __builtin_amdgcn_exp2f(sc[c][r] - m_run);
                p[c][r] = pe;
                ladd += pe;
            }
        l_run += ladd;

        #pragma unroll
        for (int kkc = 0; kkc < 2; ++kkc) {
            uint4v au;
            au[0] = cvtpk(p[2 * kkc][0],     p[2 * kkc][1]);
            au[1] = cvtpk(p[2 * kkc][2],     p[2 * kkc][3]);
            au[2] = cvtpk(p[2 * kkc + 1][0], p[2 * kkc + 1][1]);
            au[3] = cvtpk(p[2 * kkc + 1][2], p[2 * kkc + 1][3]);
            short8_t ap = __builtin_bit_cast(short8_t, au);
            #pragma unroll
            for (int dc = 0; dc < 4; ++dc) {
                int vrow = dc * 16 + l15;
                short8_t bv = *(const short8_t*)((const char*)Vb + vrow * 128 + (((kkc * 4 + g) ^ lx) * 16));
                o[dc] = __builtin_amdgcn_mfma_f32_16x16x32_bf16(ap, bv, o[dc], 0, 0, 0);
            }
        }
    };

    const int t0 = (split * 49) / 8;
    const int t1 = ((split + 1) * 49) / 8;
    int t = t0;
    for (; t + 1 < t1; t += 2) {
        stage(t, 0);
        stage(t + 1, 1);
        __syncthreads();
        compute(Ks, Vs);
        compute(Ks + 4096, Vs + 4096);
        __syncthreads();
    }
    if (t < t1) {
        stage(t, 0);
        __syncthreads();
        compute(Ks, Vs);
    }

    float l_tot = l_run;
    l_tot += __shfl_xor(l_tot, 16);
    l_tot += __shfl_xor(l_tot, 32);

    const size_t rbase = (size_t)(split * B_ + b) * N_;
    #pragma unroll
    for (int dc = 0; dc < 4; ++dc)
        #pragma unroll
        for (int r = 0; r < 4; ++r) {
            int row = q0 + w * 16 + g * 4 + r;
            osp16[(rbase + row) * 64 + dc * 16 + l15] = bf16r(o[dc][r]);
        }
    if (l < 16) {
        int row = q0 + w * 16 + l15;
        mls[(rbase + row) * 2]     = m_run;
        mls[(rbase + row) * 2 + 1] = l_tot;
    }
}

// =====================================================================
// merged fc@sh + v-conv for both branches: one block per (branch,bh)
// =====================================================================
__global__ __launch_bounds__(256)
void fcsh_vconv_kernel(const float* __restrict__ kvm1, const float* __restrict__ fc1w,
                       const float* __restrict__ sh1w, float* __restrict__ kv1,
                       const float* __restrict__ kvm2, const float* __restrict__ fc2w,
                       const float* __restrict__ sh2w, float* __restrict__ kv2,
                       const float* __restrict__ lc1w, const float* __restrict__ lc1b,
                       float* __restrict__ v1c,
                       const float* __restrict__ lc2w, const float* __restrict__ lc2b,
                       float* __restrict__ v2c) {
    int bh2 = blockIdx.x;
    const int branch = (bh2 >= 16);
    const float* kvm = branch ? kvm2 : kvm1;
    const float* fcw = branch ? fc2w : fc1w;
    const float* shw = branch ? sh2w : sh1w;
    const float* lcw = branch ? lc2w : lc1w;
    const float* lcb = branch ? lc2b : lc1b;
    float* kvout     = branch ? kv2 : kv1;
    float* vcout     = branch ? v2c : v1c;
    int bh = branch ? bh2 - 16 : bh2;
    const int h = bh % NH_;
    __shared__ float kin[49][28];
    __shared__ float tmp[49][28];
    __shared__ float fw[28 * 28];
    __shared__ float sw[28 * 56];
    __shared__ float outs[49][56];
    int t = threadIdx.x;
    for (int i = t; i < 49 * 28; i += 256) kin[i / 28][i % 28] = kvm[bh * 49 * 28 + i];
    for (int i = t; i < 28 * 28; i += 256) fw[i] = fcw[i];
    for (int i = t; i < 28 * 56; i += 256) sw[i] = shw[i];
    __syncthreads();
    for (int i = t; i < 49 * 28; i += 256) {
        int rr = i / 28, j = i % 28;
        float s = 0.f;
        for (int k = 0; k < 28; ++k) s += kin[rr][k] * fw[k * 28 + j];
        tmp[rr][j] = s;
    }
    __syncthreads();
    for (int i = t; i < 49 * 56; i += 256) {
        int rr = i / 56, j = i % 56;
        float s = 0.f;
        for (int k = 0; k < 28; ++k) s += tmp[rr][k] * sw[k * 56 + j];
        outs[rr][j] = s;
        kvout[bh * 49 * 56 + i] = s;
    }
    __syncthreads();
    for (int i = t; i < 49 * 28; i += 256) {
        int d = i % 28, n = i / 28;
        int y = n / 7, xx = n % 7;
        int c = h * HD_ + d;
        float sum = outs[n][28 + d] + lcb[c];
        #pragma unroll
        for (int ky = 0; ky < 3; ++ky)
            #pragma unroll
            for (int kx = 0; kx < 3; ++kx) {
                int yy = y + ky - 1, x2 = xx + kx - 1;
                if (yy >= 0 && yy < 7 && x2 >= 0 && x2 < 7)
                    sum += outs[yy * 7 + x2][28 + d] * lcw[c * 9 + ky * 3 + kx];
            }
        vcout[bh * 49 * 28 + i] = sum;
    }
}

// =====================================================================
// FUSED attn_local + combine
// [0,6272): attn_local; [6272,12544): combine
// =====================================================================
__global__ __launch_bounds__(256)
void fused_local_comb_kernel(const ushort_t* __restrict__ q16,
                             const float* __restrict__ kv1, const float* __restrict__ v1c,
                             const float* __restrict__ kv2, const float* __restrict__ v2c,
                             const ushort_t* __restrict__ osp16, const float* __restrict__ mls,
                             ushort_t* __restrict__ catb) {
    const int bid = blockIdx.x;
    const int tid = threadIdx.x;
    __shared__ __align__(16) ushort_t Ks[64 * 32];
    __shared__ __align__(16) ushort_t Vt[32 * 64];

    if (bid >= 6272) {
        int idx = (bid - 6272) * 256 + tid;
        int col = idx & 63;
        size_t rn = (size_t)(idx >> 6);
        const size_t BN = (size_t)B_ * N_;
        float ms[NSPLIT], ls[NSPLIT];
        float m = -3.0e38f;
        #pragma unroll
        for (int s = 0; s < NSPLIT; ++s) {
            ms[s] = mls[(s * BN + rn) * 2];
            ls[s] = mls[(s * BN + rn) * 2 + 1];
            m = fmaxf(m, ms[s]);
        }
        float lsum = 0.f, acc = 0.f;
        #pragma unroll
        for (int s = 0; s < NSPLIT; ++s) {
            float wgt = __builtin_amdgcn_exp2f(ms[s] - m);
            lsum += ls[s] * wgt;
            acc  += bf16tof(osp16[(s * BN + rn) * 64 + col]) * wgt;
        }
        catb[rn * DIM_ + col] = bf16r(acc / lsum);
        return;
    }

    const int ybh    = bid / 196;
    const int branch = ybh & 1;
    const int bh     = ybh >> 1;
    const int b      = bh >> 3, h = bh & 7;
    const int q0     = (bid % 196) * 64;
    const int w      = tid >> 6;
    const int l      = tid & 63;
    const int l15    = l & 15;
    const int g      = l >> 4;
    const float SC2K = 0.1889822365046136f * 1.44269504088896340736f;

    const float* kvsh = branch ? kv2 : kv1;
    const float* vc   = branch ? v2c : v1c;
    const int qoff    = D0_ + h * 56 + branch * 28;
    const int outoff  = (branch ? D0_ + 224 : D0_) + h * HD_;

    {
        int row = tid >> 2, lc = tid & 3;
        int pr = (row & 32) | (((row >> 2) & 3) << 3) | (((row >> 4) & 1) << 2) | (row & 3);
        uint4v u = (uint4v){0u, 0u, 0u, 0u};
        if (pr < 49) {
            const float* src = kvsh + (bh * 49 + pr) * 56 + lc * 8;
            float vv[8];
            #pragma unroll
            for (int j2 = 0; j2 < 8; ++j2)
                vv[j2] = (lc * 8 + j2 < 28) ? src[j2] * SC2K : 0.f;
            u[0] = cvtpk(vv[0], vv[1]);
            u[1] = cvtpk(vv[2], vv[3]);
            u[2] = cvtpk(vv[4], vv[5]);
            u[3] = cvtpk(vv[6], vv[7]);
        }
        *(uint4v*)(Ks + row * 32 + (lc ^ (row & 3)) * 8) = u;
    }
    {
        int row = tid >> 3, lc = tid & 7;
        uint4v u = (uint4v){0u, 0u, 0u, 0u};
        if (row < 28) {
            float vv[8];
            #pragma unroll
            for (int j2 = 0; j2 < 8; ++j2) {
                int kc = lc * 8 + j2;
                vv[j2] = (kc < 49) ? vc[(bh * 49 + kc) * 28 + row] : 0.f;
            }
            u[0] = cvtpk(vv[0], vv[1]);
            u[1] = cvtpk(vv[2], vv[3]);
            u[2] = cvtpk(vv[4], vv[5]);
            u[3] = cvtpk(vv[6], vv[7]);
        }
        *(uint4v*)(Vt + row * 64 + (lc ^ (row & 7)) * 8) = u;
    }
    short8_t qf;
    {
        const ushort_t* qp = q16 + ((size_t)b * N_ + q0 + w * 16 + l15) * DIM_ + qoff + g * 8;
        uint2v a01 = *(const uint2v*)qp;
        uint2v a23 = (g < 3) ? *(const uint2v*)(qp + 4) : (uint2v){0u, 0u};
        uint4v uv;
        uv[0] = a01[0]; uv[1] = a01[1]; uv[2] = a23[0]; uv[3] = a23[1];
        qf = __builtin_bit_cast(short8_t, uv);
    }
    __syncthreads();

    float4v sc4[4];
    #pragma unroll
    for (int c = 0; c < 4; ++c) {
        int row = c * 16 + l15;
        short8_t ak = *(const short8_t*)(Ks + row * 32 + ((g ^ (row & 3)) * 8));
        float4v acc = (float4v){0.f, 0.f, 0.f, 0.f};
        sc4[c] = __builtin_amdgcn_mfma_f32_16x16x32_bf16(ak, qf, acc, 0, 0, 0);
    }

    float tmax = fmaxf(fmaxf(fmaxf(sc4[0][0], sc4[0][1]), fmaxf(sc4[0][2], sc4[0][3])),
                       fmaxf(fmaxf(sc4[1][0], sc4[1][1]), fmaxf(sc4[1][2], sc4[1][3])));
    tmax = fmaxf(tmax, fmaxf(fmaxf(fmaxf(sc4[2][0], sc4[2][1]), fmaxf(sc4[2][2], sc4[2][3])),
                             fmaxf(fmaxf(sc4[3][0], sc4[3][1]), fmaxf(sc4[3][2], sc4[3][3]))));
    tmax = fmaxf(tmax, __shfl_xor(tmax, 16));
    tmax = fmaxf(tmax, __shfl_xor(tmax, 32));

    float p[4][4];
    float lsum = 0.f;
    #pragma unroll
    for (int c = 0; c < 4; ++c)
        #pragma unroll
        for (int r = 0; r < 4; ++r) {
            float pe = __builtin_amdgcn_exp2f(sc4[c][r] - tmax);
            if (c >= 2 && (8 * g + 4 * (c & 1) + r) >= 17) pe = 0.f;
            p[c][r] = pe;
            lsum += pe;
        }
    lsum += __shfl_xor(lsum, 16);
    lsum += __shfl_xor(lsum, 32);
    float inv = 1.0f / lsum;

    float4v o2[2];
    o2[0] = (float4v){0.f, 0.f, 0.f, 0.f};
    o2[1] = (float4v){0.f, 0.f, 0.f, 0.f};
    #pragma unroll
    for (int kkc = 0; kkc < 2; ++kkc) {
        uint4v au;
        au[0] = cvtpk(p[2 * kkc][0],     p[2 * kkc][1]);
        au[1] = cvtpk(p[2 * kkc][2],     p[2 * kkc][3]);
        au[2] = cvtpk(p[2 * kkc + 1][0], p[2 * kkc + 1][1]);
        au[3] = cvtpk(p[2 * kkc + 1][2], p[2 * kkc + 1][3]);
        short8_t ap = __builtin_bit_cast(short8_t, au);
        #pragma unroll
        for (int dc = 0; dc < 2; ++dc) {
            int vrow = dc * 16 + l15;
            short8_t bv = *(const short8_t*)(Vt + vrow * 64 + (((kkc * 4 + g) ^ (vrow & 7)) * 8));
            o2[dc] = __builtin_amdgcn_mfma_f32_16x16x32_bf16(ap, bv, o2[dc], 0, 0, 0);
        }
    }

    float irow[4];
    #pragma unroll
    for (int r = 0; r < 4; ++r) irow[r] = __shfl(inv, g * 4 + r);
    #pragma unroll
    for (int dc = 0; dc < 2; ++dc) {
        int d = dc * 16 + l15;
        if (d < 28) {
            #pragma unroll
            for (int r = 0; r < 4; ++r) {
                int row = q0 + w * 16 + g * 4 + r;
                catb[((size_t)b * N_ + row) * DIM_ + outoff + d] = bf16r(o2[dc][r] * irow[r]);
            }
        }
    }
}

// =====================================================================
extern "C" void kernel_launch(void* const* d_in, const int* in_sizes, int n_in,
                              void* d_out, int out_size, void* d_ws, size_t ws_size,
                              hipStream_t stream) {
    const float* x      = (const float*)d_in[0];
    const float* Wq     = (const float*)d_in[1];
    const float* Wkv_g  = (const float*)d_in[2];
    const float* sr_w   = (const float*)d_in[3];
    const float* sr_b   = (const float*)d_in[4];
    const float* ln_g   = (const float*)d_in[5];
    const float* ln_b   = (const float*)d_in[6];
    const float* lcg_w  = (const float*)d_in[7];
    const float* lcg_b  = (const float*)d_in[8];
    const float* kvl_dw = (const float*)d_in[9];
    const float* kvl_db = (const float*)d_in[10];
    const float* kvl_pw = (const float*)d_in[11];
    const float* kvl_pb = (const float*)d_in[12];
    const float* fc1_w  = (const float*)d_in[13];
    const float* sh1_w  = (const float*)d_in[14];
    const float* lc1_w  = (const float*)d_in[15];
    const float* lc1_b  = (const float*)d_in[16];
    const float* fc2_w  = (const float*)d_in[17];
    const float* sh2_w  = (const float*)d_in[18];
    const float* lc2_w  = (const float*)d_in[19];
    const float* lc2_b  = (const float*)d_in[20];
    const float* proj_w = (const float*)d_in[21];
    const float* proj_b = (const float*)d_in[22];
    float* out = (float*)d_out;
    char* base = (char*)d_ws;

    size_t o = 0;
    auto alloc = [&](size_t bytes) -> void* {
        void* p = base + o;
        o = (o + bytes + 255) & ~(size_t)255;
        return p;
    };
    ushort_t* q16   = (ushort_t*)alloc((size_t)B_ * N_ * DIM_ * 2);
    ushort_t* kvl16 = (ushort_t*)alloc((size_t)B_ * N_ * DL_ * 2);
    ushort_t* osp16 = (ushort_t*)alloc((size_t)NSPLIT * B_ * N_ * 64 * 2);
    float*    mls   = (float*)   alloc((size_t)NSPLIT * B_ * N_ * 2 * 4);
    ushort_t* xcat  = (ushort_t*)alloc((size_t)B_ * N_ * DIM_ * 2);  // xbf, then cat
    ushort_t* dwtb  = (ushort_t*)alloc((size_t)B_ * N_ * DL_ * 2);
    ushort_t* kgb   = (ushort_t*)alloc((size_t)B_ * NR_ * 64 * 2);
    float*    vg    = (float*)   alloc((size_t)B_ * NR_ * 64 * 4);
    ushort_t* vtb   = (ushort_t*)alloc((size_t)B_ * 64 * NR_ * 2);
    ushort_t* wqt   = (ushort_t*)alloc((size_t)512 * 512 * 2);
    ushort_t* pwt   = (ushort_t*)alloc((size_t)512 * 448 * 2);
    ushort_t* projt = (ushort_t*)alloc((size_t)512 * 512 * 2);
    float*    srwt  = (float*)   alloc((size_t)256 * 64 * 4);
    float*    kvm1  = (float*)   alloc((size_t)B_ * NH_ * 49 * HD_ * 4);
    float*    kvm2  = (float*)   alloc((size_t)B_ * NH_ * 49 * HD_ * 4);
    float*    kv1   = (float*)   alloc((size_t)B_ * NH_ * 49 * 56 * 4);
    float*    kv2   = (float*)   alloc((size_t)B_ * NH_ * 49 * 56 * 4);
    float*    v1c   = (float*)   alloc((size_t)B_ * NH_ * 49 * HD_ * 4);
    float*    v2c   = (float*)   alloc((size_t)B_ * NH_ * 49 * HD_ * 4);
    ushort_t* xbf   = xcat;
    ushort_t* catb  = xcat;

    const int M = B_ * N_;   // 25088

    // 1. merged prep
    prep_kernel<<<9280, 256, 0, stream>>>(Wq, kvl_pw, proj_w, sr_w, x,
                                          wqt, pwt, projt, srwt, xbf);

    // 2. fused: q-GEMM (dbuf) + dwt + srlnkv
    fused3_kernel<<<5096, 256, 0, stream>>>(xbf, wqt, q16,
                                            kvl_dw, kvl_db, dwtb,
                                            x, srwt, sr_b, ln_g, ln_b, Wkv_g,
                                            kgb, vg);

    // 3. fused: pointwise GEMM (dbuf) -> kvl16 + lcg/vtrans -> vtb
    fused2_kernel<<<882, 256, 0, stream>>>(dwtb, pwt, kvl_pb, kvl16,
                                           vg, lcg_w, lcg_b, vtb);

    // 4. fused: attn_global (split-K=8) + local_mean
    fused_ag_lm_kernel<<<3136, 512, 0, stream>>>(q16, kgb, vtb, osp16, mls,
                                                 kvl16, kvm1, kvm2);

    // 5. fc @ sh + v-conv (both branches, one launch)
    fcsh_vconv_kernel<<<32, 256, 0, stream>>>(kvm1, fc1_w, sh1_w, kv1,
                                              kvm2, fc2_w, sh2_w, kv2,
                                              lc1_w, lc1_b, v1c,
                                              lc2_w, lc2_b, v2c);

    // 6. fused: attn_local + combine (disjoint catb columns)
    fused_local_comb_kernel<<<12544, 256, 0, stream>>>(q16, kv1, v1c, kv2, v2c,
                                                       osp16, mls, catb);

    // 7. out = catb @ projt^T + proj_b (dbuf)
    gemm_bf16_kernel<true, false><<<dim3(M / 128, 4), 256, 0, stream>>>(
        catb, projt, proj_b, out, 512, 512, 512);
}

// Round 26
// 250.367 us; speedup vs baseline: 1.0565x; 1.0565x over previous
//
#include <hip/hip_runtime.h>
#include <hip/hip_bf16.h>
#include <math.h>
#include <stdint.h>

// ---- problem constants ----
static constexpr int B_    = 2;
static constexpr int N_    = 12544;   // 112*112
static constexpr int DIM_  = 512;
static constexpr int D0_   = 64;
static constexpr int DL_   = 448;
static constexpr int Himg  = 112;
static constexpr int Wimg  = 112;
static constexpr int HS_   = 56;
static constexpr int NR_   = 3136;    // 56*56
static constexpr int NH_   = 8;
static constexpr int HD_   = 28;
static constexpr int NSPLIT = 4;

typedef unsigned short ushort_t;
typedef __attribute__((ext_vector_type(8))) short short8_t;
typedef __attribute__((ext_vector_type(4))) float float4v;
typedef __attribute__((ext_vector_type(4))) unsigned uint4v;
typedef __attribute__((ext_vector_type(2))) unsigned uint2v;

static __device__ inline ushort_t bf16r(float x) {
    unsigned u = __builtin_bit_cast(unsigned, x);
    u = (u + 0x7FFFu + ((u >> 16) & 1u)) >> 16;
    return (ushort_t)u;
}
static __device__ inline float bf16tof(ushort_t h) {
    unsigned u = ((unsigned)h) << 16;
    return __builtin_bit_cast(float, u);
}
static __device__ inline unsigned pack_bf16(float lo, float hi) {
    unsigned a = __builtin_bit_cast(unsigned, lo);
    unsigned b = __builtin_bit_cast(unsigned, hi);
    a = (a + 0x7FFFu + ((a >> 16) & 1u)) >> 16;
    b = (b + 0x7FFFu + ((b >> 16) & 1u)) >> 16;
    return a | (b << 16);
}
static __device__ inline unsigned cvtpk(float lo, float hi) {
    float2 f2; f2.x = lo; f2.y = hi;
    __hip_bfloat162 h = __float22bfloat162_rn(f2);
    unsigned u;
    __builtin_memcpy(&u, &h, 4);
    return u;
}

using gptr_t = const __attribute__((address_space(1))) void*;
using lptr_t = __attribute__((address_space(3))) void*;
static __device__ inline void gload16(const void* g, void* l) {
    __builtin_amdgcn_global_load_lds((gptr_t)(uintptr_t)g, (lptr_t)(uintptr_t)l, 16, 0, 0);
}

// =====================================================================
// bf16 MFMA GEMM (standalone, used for proj only)
// =====================================================================
template<bool HASBIAS, bool OUT16>
__global__ __launch_bounds__(256, 2)
void gemm_bf16_kernel(const ushort_t* __restrict__ A,
                      const ushort_t* __restrict__ Bt,
                      const float* __restrict__ bias,
                      void* __restrict__ Cv,
                      int Nn, int K, int ldc) {
    constexpr int BM = 128, BK = 64;
    __shared__ __align__(16) ushort_t As[BM * BK];
    __shared__ __align__(16) ushort_t Bs[BM * BK];
    const int bm = blockIdx.x * BM;
    const int bn = blockIdx.y * BM;
    const int tid = threadIdx.x;
    const int l15 = tid & 15;
    const int g   = (tid & 63) >> 4;
    const int w   = tid >> 6;
    const int wr  = w >> 1, wc = w & 1;

    float4v acc[4][4];
    #pragma unroll
    for (int m = 0; m < 4; ++m)
        #pragma unroll
        for (int n = 0; n < 4; ++n) acc[m][n] = (float4v){0.f, 0.f, 0.f, 0.f};

    for (int k0 = 0; k0 < K; k0 += BK) {
        #pragma unroll
        for (int i = 0; i < 4; ++i) {
            int c = i * 256 + tid;
            int r = c >> 3, ch = c & 7;
            int sch = ch ^ (r & 7);
            gload16(A  + (size_t)(bm + r) * K + k0 + sch * 8, (void*)(As + c * 8));
            gload16(Bt + (size_t)(bn + r) * K + k0 + sch * 8, (void*)(Bs + c * 8));
        }
        __syncthreads();

        short8_t af[4][2], bfr[4][2];
        #pragma unroll
        for (int m = 0; m < 4; ++m) {
            int ar = wr * 64 + m * 16 + l15;
            #pragma unroll
            for (int h = 0; h < 2; ++h)
                af[m][h] = *(const short8_t*)((const char*)As + ar * 128 + (((h * 4 + g) ^ (ar & 7)) * 16));
        }
        #pragma unroll
        for (int n = 0; n < 4; ++n) {
            int br = wc * 64 + n * 16 + l15;
            #pragma unroll
            for (int h = 0; h < 2; ++h)
                bfr[n][h] = *(const short8_t*)((const char*)Bs + br * 128 + (((h * 4 + g) ^ (br & 7)) * 16));
        }
        #pragma unroll
        for (int m = 0; m < 4; ++m)
            #pragma unroll
            for (int n = 0; n < 4; ++n) {
                acc[m][n] = __builtin_amdgcn_mfma_f32_16x16x32_bf16(af[m][0], bfr[n][0], acc[m][n], 0, 0, 0);
                acc[m][n] = __builtin_amdgcn_mfma_f32_16x16x32_bf16(af[m][1], bfr[n][1], acc[m][n], 0, 0, 0);
            }
        __syncthreads();
    }

    #pragma unroll
    for (int n = 0; n < 4; ++n) {
        int ccol = bn + wc * 64 + n * 16 + l15;
        if (ccol < Nn) {
            float bv = HASBIAS ? bias[ccol] : 0.f;
            #pragma unroll
            for (int m = 0; m < 4; ++m) {
                int crow = bm + wr * 64 + m * 16 + g * 4;
                #pragma unroll
                for (int j = 0; j < 4; ++j) {
                    float v = acc[m][n][j] + bv;
                    if (OUT16)
                        ((ushort_t*)Cv)[(size_t)(crow + j) * ldc + ccol] = bf16r(v);
                    else
                        ((float*)Cv)[(size_t)(crow + j) * ldc + ccol] = v;
                }
            }
        }
    }
}

// =====================================================================
// merged prep: wqt, pwt, projt, srwt, xbf
// =====================================================================
__global__ __launch_bounds__(256)
void prep_kernel(const float* __restrict__ Wq, const float* __restrict__ kvl_pw,
                 const float* __restrict__ proj_w, const float* __restrict__ sr_w,
                 const float* __restrict__ x,
                 ushort_t* __restrict__ wqt, ushort_t* __restrict__ pwt,
                 ushort_t* __restrict__ projt, float* __restrict__ srwt,
                 ushort_t* __restrict__ xbf) {
    int idx = blockIdx.x * 256 + threadIdx.x;
    if (idx < 262144) {
        int n = idx >> 9, k = idx & 511;
        wqt[idx] = bf16r(Wq[(size_t)k * 512 + n]);
    } else if (idx < 491520) {
        int i = idx - 262144;
        int n = i / 448, k = i % 448;
        float v = (n < 448) ? kvl_pw[(size_t)n * 448 + k] : 0.f;
        pwt[i] = bf16r(v);
    } else if (idx < 753664) {
        int i = idx - 491520;
        int n = i >> 9, k = i & 511;
        projt[i] = bf16r(proj_w[(size_t)k * 512 + n]);
    } else if (idx < 770048) {
        int i = idx - 753664;
        int f = i >> 6, o2 = i & 63;
        srwt[i] = sr_w[o2 * 256 + f];
    } else {
        int i = idx - 770048;
        const float4v* p = (const float4v*)(x + (size_t)i * 8);
        float4v a = p[0], b = p[1];
        uint4v u;
        u[0] = pack_bf16(a[0], a[1]);
        u[1] = pack_bf16(a[2], a[3]);
        u[2] = pack_bf16(b[0], b[1]);
        u[3] = pack_bf16(b[2], b[3]);
        *(uint4v*)(xbf + (size_t)i * 8) = u;
    }
}

// =====================================================================
// FUSED3: [0,784) q-GEMM | [784,3528) dwt | [3528,5096) srlnkv x4
// single 32KB LDS union across branches (occupancy-friendly)
// =====================================================================
__global__ __launch_bounds__(256, 2)
void fused3_kernel(const ushort_t* __restrict__ xbf, const ushort_t* __restrict__ wqt,
                   ushort_t* __restrict__ q16,
                   const float* __restrict__ kvl_dw, const float* __restrict__ kvl_db,
                   ushort_t* __restrict__ dwtb,
                   const float* __restrict__ x, const float* __restrict__ srwt,
                   const float* __restrict__ sr_b, const float* __restrict__ ln_g,
                   const float* __restrict__ ln_b, const float* __restrict__ wkv,
                   ushort_t* __restrict__ kgb, float* __restrict__ vg) {
    const int bid = blockIdx.x;
    const int tid = threadIdx.x;
    __shared__ __align__(16) char smem[32768];

    if (bid < 784) {
        ushort_t* As = (ushort_t*)smem;
        ushort_t* Bs = (ushort_t*)(smem + 16384);
        const int bm = (bid % 196) * 128;
        const int bn = (bid / 196) * 128;
        const int l15 = tid & 15;
        const int g   = (tid & 63) >> 4;
        const int w   = tid >> 6;
        const int wr  = w >> 1, wc = w & 1;
        float4v acc[4][4];
        #pragma unroll
        for (int m = 0; m < 4; ++m)
            #pragma unroll
            for (int n = 0; n < 4; ++n) acc[m][n] = (float4v){0.f, 0.f, 0.f, 0.f};
        for (int k0 = 0; k0 < 512; k0 += 64) {
            #pragma unroll
            for (int i = 0; i < 4; ++i) {
                int c = i * 256 + tid;
                int r = c >> 3, ch = c & 7;
                int sch = ch ^ (r & 7);
                gload16(xbf + (size_t)(bm + r) * 512 + k0 + sch * 8, (void*)(As + c * 8));
                gload16(wqt + (size_t)(bn + r) * 512 + k0 + sch * 8, (void*)(Bs + c * 8));
            }
            __syncthreads();
            short8_t af[4][2], bfr[4][2];
            #pragma unroll
            for (int m = 0; m < 4; ++m) {
                int ar = wr * 64 + m * 16 + l15;
                #pragma unroll
                for (int h = 0; h < 2; ++h)
                    af[m][h] = *(const short8_t*)((const char*)As + ar * 128 + (((h * 4 + g) ^ (ar & 7)) * 16));
            }
            #pragma unroll
            for (int n = 0; n < 4; ++n) {
                int br = wc * 64 + n * 16 + l15;
                #pragma unroll
                for (int h = 0; h < 2; ++h)
                    bfr[n][h] = *(const short8_t*)((const char*)Bs + br * 128 + (((h * 4 + g) ^ (br & 7)) * 16));
            }
            #pragma unroll
            for (int m = 0; m < 4; ++m)
                #pragma unroll
                for (int n = 0; n < 4; ++n) {
                    acc[m][n] = __builtin_amdgcn_mfma_f32_16x16x32_bf16(af[m][0], bfr[n][0], acc[m][n], 0, 0, 0);
                    acc[m][n] = __builtin_amdgcn_mfma_f32_16x16x32_bf16(af[m][1], bfr[n][1], acc[m][n], 0, 0, 0);
                }
            __syncthreads();
        }
        #pragma unroll
        for (int n = 0; n < 4; ++n) {
            int ccol = bn + wc * 64 + n * 16 + l15;
            #pragma unroll
            for (int m = 0; m < 4; ++m) {
                int crow = bm + wr * 64 + m * 16 + g * 4;
                #pragma unroll
                for (int j = 0; j < 4; ++j)
                    q16[(size_t)(crow + j) * 512 + ccol] = bf16r(acc[m][n][j]);
            }
        }
    } else if (bid < 3528) {
        int idx = (bid - 784) * 256 + tid;
        int c4 = idx % 112;
        int t1 = idx / 112;
        int xx = t1 % 112;
        int t2 = t1 / 112;
        int yg = t2 % 28;
        int b  = t2 / 28;
        int c0 = c4 * 4;
        int y0 = yg * 4;
        float4v w4[9];
        #pragma unroll
        for (int kt = 0; kt < 9; ++kt) {
            w4[kt][0] = kvl_dw[(c0 + 0) * 9 + kt];
            w4[kt][1] = kvl_dw[(c0 + 1) * 9 + kt];
            w4[kt][2] = kvl_dw[(c0 + 2) * 9 + kt];
            w4[kt][3] = kvl_dw[(c0 + 3) * 9 + kt];
        }
        float4v bv = *(const float4v*)(kvl_db + c0);
        float4v acc[4];
        #pragma unroll
        for (int o2 = 0; o2 < 4; ++o2) acc[o2] = bv;
        #pragma unroll
        for (int yy = 0; yy < 6; ++yy) {
            int Y = y0 - 1 + yy;
            if (Y < 0 || Y >= Himg) continue;
            #pragma unroll
            for (int xt = 0; xt < 3; ++xt) {
                int X = xx - 1 + xt;
                if (X < 0 || X >= Wimg) continue;
                uint2v q2 = *(const uint2v*)(xbf + ((size_t)b * N_ + Y * Wimg + X) * DIM_ + D0_ + c0);
                float4v v;
                v[0] = bf16tof((ushort_t)(q2[0] & 0xffffu));
                v[1] = bf16tof((ushort_t)(q2[0] >> 16));
                v[2] = bf16tof((ushort_t)(q2[1] & 0xffffu));
                v[3] = bf16tof((ushort_t)(q2[1] >> 16));
                constexpr int olo_t[6] = {0, 0, 0, 1, 2, 3};
                constexpr int ohi_t[6] = {0, 1, 2, 3, 3, 3};
                #pragma unroll
                for (int o2 = olo_t[yy]; o2 <= ohi_t[yy]; ++o2) {
                    float4v wv = w4[(yy - o2) * 3 + xt];
                    acc[o2][0] += v[0] * wv[0];
                    acc[o2][1] += v[1] * wv[1];
                    acc[o2][2] += v[2] * wv[2];
                    acc[o2][3] += v[3] * wv[3];
                }
            }
        }
        #pragma unroll
        for (int o2 = 0; o2 < 4; ++o2) {
            uint2v pk;
            pk[0] = pack_bf16(acc[o2][0], acc[o2][1]);
            pk[1] = pack_bf16(acc[o2][2], acc[o2][3]);
            *(uint2v*)(dwtb + ((size_t)b * N_ + (y0 + o2) * Wimg + xx) * DL_ + c0) = pk;
        }
    } else {
        // srlnkv: 4 positions per block; LDS overlays smem
        float* xs    = (float*)smem;            // [grp*256 + tap*64 + o], 4KB
        float* lnv_s = (float*)(smem + 4096);   // [grp*64 + o], 1KB
        const int blk4 = bid - 3528;
        const int grp  = tid >> 6;
        const int o    = tid & 63;
        const int pos  = blk4 * 4 + grp;
        const int b = pos / NR_, n = pos % NR_;
        const int y = n / HS_, xx = n % HS_;
        #pragma unroll
        for (int tap = 0; tap < 4; ++tap) {
            int ky = tap / 2, kx = tap % 2;
            xs[grp * 256 + tap * 64 + o] =
                x[((size_t)b * N_ + (2 * y + ky) * Wimg + 2 * xx + kx) * DIM_ + o];
        }
        __syncthreads();
        float sum = sr_b[o];
        for (int i = 0; i < 64; ++i) {
            const float* wr = srwt + (i * 4) * 64 + o;
            sum += xs[grp * 256 + 0 * 64 + i] * wr[0] + xs[grp * 256 + 1 * 64 + i] * wr[64]
                 + xs[grp * 256 + 2 * 64 + i] * wr[128] + xs[grp * 256 + 3 * 64 + i] * wr[192];
        }
        float m = sum;
        #pragma unroll
        for (int off = 1; off < 64; off <<= 1) m += __shfl_xor(m, off);
        m *= (1.0f / 64.0f);
        float d = sum - m;
        float v = d * d;
        #pragma unroll
        for (int off = 1; off < 64; off <<= 1) v += __shfl_xor(v, off);
        v *= (1.0f / 64.0f);
        float lnv = d * rsqrtf(v + 1e-5f) * ln_g[o] + ln_b[o];
        lnv_s[grp * 64 + o] = lnv;
        __syncthreads();
        float s0 = 0.f, s1 = 0.f;
        for (int i = 0; i < 64; ++i) {
            float lv = lnv_s[grp * 64 + i];
            s0 += lv * wkv[i * 128 + o];
            s1 += lv * wkv[i * 128 + o + 64];
        }
        const float SCK = 0.125f * 1.44269504088896340736f;
        kgb[((size_t)b * NR_ + n) * 64 + o] = bf16r(s0 * SCK);
        vg[((size_t)b * NR_ + n) * 64 + o] = s1;
    }
}

// =====================================================================
// FUSED2: [0,784) pointwise GEMM -> kvl16 | [784,882) lcg+vtrans
// single 32KB LDS union
// =====================================================================
__global__ __launch_bounds__(256, 2)
void fused2_kernel(const ushort_t* __restrict__ dwtb, const ushort_t* __restrict__ pwt,
                   const float* __restrict__ kvl_pb, ushort_t* __restrict__ kvl16,
                   const float* __restrict__ vg, const float* __restrict__ lcg_w,
                   const float* __restrict__ lcg_b, ushort_t* __restrict__ vtb) {
    const int bid = blockIdx.x;
    const int tid = threadIdx.x;
    __shared__ __align__(16) char smem[32768];

    if (bid < 784) {
        ushort_t* As = (ushort_t*)smem;
        ushort_t* Bs = (ushort_t*)(smem + 16384);
        const int bm = (bid % 196) * 128;
        const int bn = (bid / 196) * 128;
        const int l15 = tid & 15;
        const int g   = (tid & 63) >> 4;
        const int w   = tid >> 6;
        const int wr  = w >> 1, wc = w & 1;
        float4v acc[4][4];
        #pragma unroll
        for (int m = 0; m < 4; ++m)
            #pragma unroll
            for (int n = 0; n < 4; ++n) acc[m][n] = (float4v){0.f, 0.f, 0.f, 0.f};
        for (int k0 = 0; k0 < 448; k0 += 64) {
            #pragma unroll
            for (int i = 0; i < 4; ++i) {
                int c = i * 256 + tid;
                int r = c >> 3, ch = c & 7;
                int sch = ch ^ (r & 7);
                gload16(dwtb + (size_t)(bm + r) * 448 + k0 + sch * 8, (void*)(As + c * 8));
                gload16(pwt  + (size_t)(bn + r) * 448 + k0 + sch * 8, (void*)(Bs + c * 8));
            }
            __syncthreads();
            short8_t af[4][2], bfr[4][2];
            #pragma unroll
            for (int m = 0; m < 4; ++m) {
                int ar = wr * 64 + m * 16 + l15;
                #pragma unroll
                for (int h = 0; h < 2; ++h)
                    af[m][h] = *(const short8_t*)((const char*)As + ar * 128 + (((h * 4 + g) ^ (ar & 7)) * 16));
            }
            #pragma unroll
            for (int n = 0; n < 4; ++n) {
                int br = wc * 64 + n * 16 + l15;
                #pragma unroll
                for (int h = 0; h < 2; ++h)
                    bfr[n][h] = *(const short8_t*)((const char*)Bs + br * 128 + (((h * 4 + g) ^ (br & 7)) * 16));
            }
            #pragma unroll
            for (int m = 0; m < 4; ++m)
                #pragma unroll
                for (int n = 0; n < 4; ++n) {
                    acc[m][n] = __builtin_amdgcn_mfma_f32_16x16x32_bf16(af[m][0], bfr[n][0], acc[m][n], 0, 0, 0);
                    acc[m][n] = __builtin_amdgcn_mfma_f32_16x16x32_bf16(af[m][1], bfr[n][1], acc[m][n], 0, 0, 0);
                }
            __syncthreads();
        }
        #pragma unroll
        for (int n = 0; n < 4; ++n) {
            int ccol = bn + wc * 64 + n * 16 + l15;
            if (ccol < 448) {
                float bv = kvl_pb[ccol];
                #pragma unroll
                for (int m = 0; m < 4; ++m) {
                    int crow = bm + wr * 64 + m * 16 + g * 4;
                    #pragma unroll
                    for (int j = 0; j < 4; ++j)
                        kvl16[(size_t)(crow + j) * 448 + ccol] = bf16r(acc[m][n][j] + bv);
                }
            }
        }
    } else {
        float* ld = (float*)smem;   // [n*65 + c], 64*65*4 = 16.6KB
        const int lb = bid - 784;
        const int b = lb / 49, n0 = (lb % 49) * 64;
        #pragma unroll
        for (int i = 0; i < 16; ++i) {
            int idx = i * 256 + tid;
            int n = idx >> 6, c = idx & 63;
            int nn = n0 + n;
            int y = nn / HS_, xx = nn % HS_;
            float sum = vg[((size_t)b * NR_ + nn) * 64 + c] + lcg_b[c];
            #pragma unroll
            for (int ky = 0; ky < 3; ++ky)
                #pragma unroll
                for (int kx = 0; kx < 3; ++kx) {
                    int yy = y + ky - 1, x2 = xx + kx - 1;
                    if (yy >= 0 && yy < HS_ && x2 >= 0 && x2 < HS_)
                        sum += vg[((size_t)b * NR_ + yy * HS_ + x2) * 64 + c] * lcg_w[c * 9 + ky * 3 + kx];
                }
            ld[n * 65 + c] = sum;
        }
        __syncthreads();
        #pragma unroll
        for (int i = 0; i < 16; ++i) {
            int idx = i * 256 + tid;
            int d = idx >> 6, nn = idx & 63;
            vtb[(size_t)(b * 64 + d) * NR_ + n0 + nn] = bf16r(ld[nn * 65 + d]);
        }
    }
}

// =====================================================================
// "scrambled mean" body (bf16 kvl), shared mem passed in
// =====================================================================
template<int L, int NBW, int STRIDE, int DIL, int CHOFF>
__device__ inline void lm_body(int blk, int t, float* slo, float* shi,
                               const ushort_t* __restrict__ kvl16,
                               float* __restrict__ kvm) {
    const int n = blk % 49;
    const int h = (blk / 49) % NH_;
    const int b = blk / (49 * NH_);
    const int wy = n / 7, wx = n % 7;

    if (t < L) {
        const int by = t / NBW, bx = t % NBW;
        int Y = by * STRIDE + DIL * wy;
        int X = bx * STRIDE + DIL * wx;
        if (Y >= Himg) Y = 2 * Himg - 2 - Y;
        if (X >= Wimg) X = 2 * Wimg - 2 - X;
        const ushort_t* src = kvl16 + ((size_t)b * N_ + Y * Wimg + X) * DL_ + CHOFF + h * HD_;
        float v[28];
        #pragma unroll
        for (int i = 0; i < 7; ++i) {
            uint2v q2 = ((const uint2v*)src)[i];
            v[i * 4]     = bf16tof((ushort_t)(q2[0] & 0xffffu));
            v[i * 4 + 1] = bf16tof((ushort_t)(q2[0] >> 16));
            v[i * 4 + 2] = bf16tof((ushort_t)(q2[1] & 0xffffu));
            v[i * 4 + 3] = bf16tof((ushort_t)(q2[1] >> 16));
        }
        const int f0 = t * HD_;
        const int bin0 = f0 / L;
        const int nlo = min(HD_, (bin0 + 1) * L - f0);
        float s0 = 0.f, s1 = 0.f;
        #pragma unroll
        for (int j = 0; j < HD_; ++j) {
            if (j < nlo) s0 += v[j]; else s1 += v[j];
        }
        slo[t] = s0;
        shi[t] = s1;
    }
    __syncthreads();
    if (t < HD_) {
        const int t_lo = (t * L) / HD_;
        const int t_hi = min(L - 1, (t * L + L - 1) / HD_);
        float sum = 0.f;
        for (int u = t_lo; u <= t_hi; ++u) {
            int f0 = u * HD_;
            int b0 = f0 / L;
            int b1 = (f0 + HD_ - 1) / L;
            if (b0 == t) sum += slo[u];
            if (b1 == t && b1 != b0) sum += shi[u];
        }
        kvm[(size_t)blk * HD_ + t] = sum * (1.0f / (float)L);
    }
}

// =====================================================================
// FUSED attn_global (split-K=4) + local_mean (32KB LDS union)
// [0,784): attn_global (512 thr); [784,2352): lm
// =====================================================================
__global__ __launch_bounds__(512)
void fused_ag_lm_kernel(const ushort_t* __restrict__ q16,
                        const ushort_t* __restrict__ kgb,
                        const ushort_t* __restrict__ vtb,
                        ushort_t* __restrict__ osp16, float* __restrict__ mls,
                        const ushort_t* __restrict__ kvl16,
                        float* __restrict__ kvm1, float* __restrict__ kvm2) {
    const int bid = blockIdx.x;
    const int tid = threadIdx.x;
    __shared__ __align__(16) char smem[32768];
    ushort_t* Ks = (ushort_t*)smem;
    ushort_t* Vs = (ushort_t*)(smem + 16384);

    if (bid >= 784) {
        float* slo = (float*)smem;            // up to 256 floats
        float* shi = (float*)(smem + 1024);
        int lmid = bid - 784;
        int blk = lmid % 784;
        if (lmid < 784) lm_body<256, 16, 7, 1, 0>(blk, tid, slo, shi, kvl16, kvm1);
        else            lm_body<81, 9, 13, 2, 224>(blk, tid, slo, shi, kvl16, kvm2);
        return;
    }

    const int split = (bid / 98) & 3;
    const int b     = (bid / 98) >> 2;
    const int q0    = (bid % 98) * 128;
    const int w     = tid >> 6;
    const int l     = tid & 63;
    const int l15   = l & 15;
    const int g     = l >> 4;
    const int lx    = l15 & 7;

    short8_t qf[2];
    {
        const ushort_t* qrow = q16 + ((size_t)b * N_ + q0 + w * 16 + l15) * DIM_;
        qf[0] = *(const short8_t*)(qrow + g * 8);
        qf[1] = *(const short8_t*)(qrow + g * 8 + 32);
    }

    float4v o[4];
    #pragma unroll
    for (int i = 0; i < 4; ++i) o[i] = (float4v){0.f, 0.f, 0.f, 0.f};
    float m_run = -3.0e38f, l_run = 0.f;

    const int stg_r   = tid >> 3;
    const int stg_sch = (tid & 7) ^ (stg_r & 7);
    const int stg_pr  = (stg_r & 32) | (((stg_r >> 2) & 3) << 3) | (((stg_r >> 4) & 1) << 2) | (stg_r & 3);
    auto stage = [&](int t, int buf) {
        const int k0 = t * 64;
        gload16(kgb + ((size_t)(b * NR_ + k0 + stg_pr) << 6) + stg_sch * 8,
                (void*)(Ks + buf * 4096 + tid * 8));
        gload16(vtb + (size_t)(b * 64 + stg_r) * NR_ + k0 + stg_sch * 8,
                (void*)(Vs + buf * 4096 + tid * 8));
    };

    auto compute = [&](const ushort_t* Kb, const ushort_t* Vb) {
        float4v sc[4];
        #pragma unroll
        for (int c = 0; c < 4; ++c) {
            float4v acc = (float4v){0.f, 0.f, 0.f, 0.f};
            #pragma unroll
            for (int dc = 0; dc < 2; ++dc) {
                int row = c * 16 + l15;
                short8_t ak = *(const short8_t*)((const char*)Kb + row * 128 + (((g + 4 * dc) ^ lx) * 16));
                acc = __builtin_amdgcn_mfma_f32_16x16x32_bf16(ak, qf[dc], acc, 0, 0, 0);
            }
            sc[c] = acc;
        }

        float tmax = fmaxf(fmaxf(fmaxf(sc[0][0], sc[0][1]), fmaxf(sc[0][2], sc[0][3])),
                           fmaxf(fmaxf(sc[1][0], sc[1][1]), fmaxf(sc[1][2], sc[1][3])));
        tmax = fmaxf(tmax, fmaxf(fmaxf(fmaxf(sc[2][0], sc[2][1]), fmaxf(sc[2][2], sc[2][3])),
                                 fmaxf(fmaxf(sc[3][0], sc[3][1]), fmaxf(sc[3][2], sc[3][3]))));

        if (__any(tmax > m_run + 11.0f)) {
            float rmax = fmaxf(tmax, __shfl_xor(tmax, 16));
            rmax = fmaxf(rmax, __shfl_xor(rmax, 32));
            float m_new = fmaxf(m_run, rmax);
            float corr = __builtin_amdgcn_exp2f(m_run - m_new);
            float co[4];
            #pragma unroll
            for (int r = 0; r < 4; ++r) co[r] = __shfl(corr, g * 4 + r);
            #pragma unroll
            for (int dc = 0; dc < 4; ++dc)
                #pragma unroll
                for (int r = 0; r < 4; ++r) o[dc][r] *= co[r];
            l_run *= corr;
            m_run = m_new;
        }

        float p[4][4];
        float ladd = 0.f;
        #pragma unroll
        for (int c = 0; c < 4; ++c)
            #pragma unroll
            for (int r = 0; r < 4; ++r) {
                float pe = __builtin_amdgcn_exp2f(sc[c][r] - m_run);
                p[c][r] = pe;
                ladd += pe;
            }
        l_run += ladd;

        #pragma unroll
        for (int kkc = 0; kkc < 2; ++kkc) {
            uint4v au;
            au[0] = cvtpk(p[2 * kkc][0],     p[2 * kkc][1]);
            au[1] = cvtpk(p[2 * kkc][2],     p[2 * kkc][3]);
            au[2] = cvtpk(p[2 * kkc + 1][0], p[2 * kkc + 1][1]);
            au[3] = cvtpk(p[2 * kkc + 1][2], p[2 * kkc + 1][3]);
            short8_t ap = __builtin_bit_cast(short8_t, au);
            #pragma unroll
            for (int dc = 0; dc < 4; ++dc) {
                int vrow = dc * 16 + l15;
                short8_t bv = *(const short8_t*)((const char*)Vb + vrow * 128 + (((kkc * 4 + g) ^ lx) * 16));
                o[dc] = __builtin_amdgcn_mfma_f32_16x16x32_bf16(ap, bv, o[dc], 0, 0, 0);
            }
        }
    };

    const int t0 = (split * 49) / 4;
    const int t1 = ((split + 1) * 49) / 4;
    int t = t0;
    for (; t + 1 < t1; t += 2) {
        stage(t, 0);
        stage(t + 1, 1);
        __syncthreads();
        compute(Ks, Vs);
        compute(Ks + 4096, Vs + 4096);
        __syncthreads();
    }
    if (t < t1) {
        stage(t, 0);
        __syncthreads();
        compute(Ks, Vs);
    }

    float l_tot = l_run;
    l_tot += __shfl_xor(l_tot, 16);
    l_tot += __shfl_xor(l_tot, 32);

    const size_t rbase = (size_t)(split * B_ + b) * N_;
    #pragma unroll
    for (int dc = 0; dc < 4; ++dc)
        #pragma unroll
        for (int r = 0; r < 4; ++r) {
            int row = q0 + w * 16 + g * 4 + r;
            osp16[(rbase + row) * 64 + dc * 16 + l15] = bf16r(o[dc][r]);
        }
    if (l < 16) {
        int row = q0 + w * 16 + l15;
        mls[(rbase + row) * 2]     = m_run;
        mls[(rbase + row) * 2 + 1] = l_tot;
    }
}

// =====================================================================
// merged fc@sh + v-conv for both branches: one block per (branch,bh)
// =====================================================================
__global__ __launch_bounds__(256)
void fcsh_vconv_kernel(const float* __restrict__ kvm1, const float* __restrict__ fc1w,
                       const float* __restrict__ sh1w, float* __restrict__ kv1,
                       const float* __restrict__ kvm2, const float* __restrict__ fc2w,
                       const float* __restrict__ sh2w, float* __restrict__ kv2,
                       const float* __restrict__ lc1w, const float* __restrict__ lc1b,
                       float* __restrict__ v1c,
                       const float* __restrict__ lc2w, const float* __restrict__ lc2b,
                       float* __restrict__ v2c) {
    int bh2 = blockIdx.x;
    const int branch = (bh2 >= 16);
    const float* kvm = branch ? kvm2 : kvm1;
    const float* fcw = branch ? fc2w : fc1w;
    const float* shw = branch ? sh2w : sh1w;
    const float* lcw = branch ? lc2w : lc1w;
    const float* lcb = branch ? lc2b : lc1b;
    float* kvout     = branch ? kv2 : kv1;
    float* vcout     = branch ? v2c : v1c;
    int bh = branch ? bh2 - 16 : bh2;
    const int h = bh % NH_;
    __shared__ float kin[49][28];
    __shared__ float tmp[49][28];
    __shared__ float fw[28 * 28];
    __shared__ float sw[28 * 56];
    __shared__ float outs[49][56];
    int t = threadIdx.x;
    for (int i = t; i < 49 * 28; i += 256) kin[i / 28][i % 28] = kvm[bh * 49 * 28 + i];
    for (int i = t; i < 28 * 28; i += 256) fw[i] = fcw[i];
    for (int i = t; i < 28 * 56; i += 256) sw[i] = shw[i];
    __syncthreads();
    for (int i = t; i < 49 * 28; i += 256) {
        int rr = i / 28, j = i % 28;
        float s = 0.f;
        for (int k = 0; k < 28; ++k) s += kin[rr][k] * fw[k * 28 + j];
        tmp[rr][j] = s;
    }
    __syncthreads();
    for (int i = t; i < 49 * 56; i += 256) {
        int rr = i / 56, j = i % 56;
        float s = 0.f;
        for (int k = 0; k < 28; ++k) s += tmp[rr][k] * sw[k * 56 + j];
        outs[rr][j] = s;
        kvout[bh * 49 * 56 + i] = s;
    }
    __syncthreads();
    for (int i = t; i < 49 * 28; i += 256) {
        int d = i % 28, n = i / 28;
        int y = n / 7, xx = n % 7;
        int c = h * HD_ + d;
        float sum = outs[n][28 + d] + lcb[c];
        #pragma unroll
        for (int ky = 0; ky < 3; ++ky)
            #pragma unroll
            for (int kx = 0; kx < 3; ++kx) {
                int yy = y + ky - 1, x2 = xx + kx - 1;
                if (yy >= 0 && yy < 7 && x2 >= 0 && x2 < 7)
                    sum += outs[yy * 7 + x2][28 + d] * lcw[c * 9 + ky * 3 + kx];
            }
        vcout[bh * 49 * 28 + i] = sum;
    }
}

// =====================================================================
// FUSED attn_local + combine
// [0,6272): attn_local; [6272,12544): combine
// =====================================================================
__global__ __launch_bounds__(256)
void fused_local_comb_kernel(const ushort_t* __restrict__ q16,
                             const float* __restrict__ kv1, const float* __restrict__ v1c,
                             const float* __restrict__ kv2, const float* __restrict__ v2c,
                             const ushort_t* __restrict__ osp16, const float* __restrict__ mls,
                             ushort_t* __restrict__ catb) {
    const int bid = blockIdx.x;
    const int tid = threadIdx.x;
    __shared__ __align__(16) ushort_t Ks[64 * 32];
    __shared__ __align__(16) ushort_t Vt[32 * 64];

    if (bid >= 6272) {
        int idx = (bid - 6272) * 256 + tid;
        int col = idx & 63;
        size_t rn = (size_t)(idx >> 6);
        const size_t BN = (size_t)B_ * N_;
        float ms[NSPLIT], ls[NSPLIT];
        float m = -3.0e38f;
        #pragma unroll
        for (int s = 0; s < NSPLIT; ++s) {
            ms[s] = mls[(s * BN + rn) * 2];
            ls[s] = mls[(s * BN + rn) * 2 + 1];
            m = fmaxf(m, ms[s]);
        }
        float lsum = 0.f, acc = 0.f;
        #pragma unroll
        for (int s = 0; s < NSPLIT; ++s) {
            float wgt = __builtin_amdgcn_exp2f(ms[s] - m);
            lsum += ls[s] * wgt;
            acc  += bf16tof(osp16[(s * BN + rn) * 64 + col]) * wgt;
        }
        catb[rn * DIM_ + col] = bf16r(acc / lsum);
        return;
    }

    const int ybh    = bid / 196;
    const int branch = ybh & 1;
    const int bh     = ybh >> 1;
    const int b      = bh >> 3, h = bh & 7;
    const int q0     = (bid % 196) * 64;
    const int w      = tid >> 6;
    const int l      = tid & 63;
    const int l15    = l & 15;
    const int g      = l >> 4;
    const float SC2K = 0.1889822365046136f * 1.44269504088896340736f;

    const float* kvsh = branch ? kv2 : kv1;
    const float* vc   = branch ? v2c : v1c;
    const int qoff    = D0_ + h * 56 + branch * 28;
    const int outoff  = (branch ? D0_ + 224 : D0_) + h * HD_;

    {
        int row = tid >> 2, lc = tid & 3;
        int pr = (row & 32) | (((row >> 2) & 3) << 3) | (((row >> 4) & 1) << 2) | (row & 3);
        uint4v u = (uint4v){0u, 0u, 0u, 0u};
        if (pr < 49) {
            const float* src = kvsh + (bh * 49 + pr) * 56 + lc * 8;
            float vv[8];
            #pragma unroll
            for (int j2 = 0; j2 < 8; ++j2)
                vv[j2] = (lc * 8 + j2 < 28) ? src[j2] * SC2K : 0.f;
            u[0] = cvtpk(vv[0], vv[1]);
            u[1] = cvtpk(vv[2], vv[3]);
            u[2] = cvtpk(vv[4], vv[5]);
            u[3] = cvtpk(vv[6], vv[7]);
        }
        *(uint4v*)(Ks + row * 32 + (lc ^ (row & 3)) * 8) = u;
    }
    {
        int row = tid >> 3, lc = tid & 7;
        uint4v u = (uint4v){0u, 0u, 0u, 0u};
        if (row < 28) {
            float vv[8];
            #pragma unroll
            for (int j2 = 0; j2 < 8; ++j2) {
                int kc = lc * 8 + j2;
                vv[j2] = (kc < 49) ? vc[(bh * 49 + kc) * 28 + row] : 0.f;
            }
            u[0] = cvtpk(vv[0], vv[1]);
            u[1] = cvtpk(vv[2], vv[3]);
            u[2] = cvtpk(vv[4], vv[5]);
            u[3] = cvtpk(vv[6], vv[7]);
        }
        *(uint4v*)(Vt + row * 64 + (lc ^ (row & 7)) * 8) = u;
    }
    short8_t qf;
    {
        const ushort_t* qp = q16 + ((size_t)b * N_ + q0 + w * 16 + l15) * DIM_ + qoff + g * 8;
        uint2v a01 = *(const uint2v*)qp;
        uint2v a23 = (g < 3) ? *(const uint2v*)(qp + 4) : (uint2v){0u, 0u};
        uint4v uv;
        uv[0] = a01[0]; uv[1] = a01[1]; uv[2] = a23[0]; uv[3] = a23[1];
        qf = __builtin_bit_cast(short8_t, uv);
    }
    __syncthreads();

    float4v sc4[4];
    #pragma unroll
    for (int c = 0; c < 4; ++c) {
        int row = c * 16 + l15;
        short8_t ak = *(const short8_t*)(Ks + row * 32 + ((g ^ (row & 3)) * 8));
        float4v acc = (float4v){0.f, 0.f, 0.f, 0.f};
        sc4[c] = __builtin_amdgcn_mfma_f32_16x16x32_bf16(ak, qf, acc, 0, 0, 0);
    }

    float tmax = fmaxf(fmaxf(fmaxf(sc4[0][0], sc4[0][1]), fmaxf(sc4[0][2], sc4[0][3])),
                       fmaxf(fmaxf(sc4[1][0], sc4[1][1]), fmaxf(sc4[1][2], sc4[1][3])));
    tmax = fmaxf(tmax, fmaxf(fmaxf(fmaxf(sc4[2][0], sc4[2][1]), fmaxf(sc4[2][2], sc4[2][3])),
                             fmaxf(fmaxf(sc4[3][0], sc4[3][1]), fmaxf(sc4[3][2], sc4[3][3]))));
    tmax = fmaxf(tmax, __shfl_xor(tmax, 16));
    tmax = fmaxf(tmax, __shfl_xor(tmax, 32));

    float p[4][4];
    float lsum = 0.f;
    #pragma unroll
    for (int c = 0; c < 4; ++c)
        #pragma unroll
        for (int r = 0; r < 4; ++r) {
            float pe = __builtin_amdgcn_exp2f(sc4[c][r] - tmax);
            if (c >= 2 && (8 * g + 4 * (c & 1) + r) >= 17) pe = 0.f;
            p[c][r] = pe;
            lsum += pe;
        }
    lsum += __shfl_xor(lsum, 16);
    lsum += __shfl_xor(lsum, 32);
    float inv = 1.0f / lsum;

    float4v o2[2];
    o2[0] = (float4v){0.f, 0.f, 0.f, 0.f};
    o2[1] = (float4v){0.f, 0.f, 0.f, 0.f};
    #pragma unroll
    for (int kkc = 0; kkc < 2; ++kkc) {
        uint4v au;
        au[0] = cvtpk(p[2 * kkc][0],     p[2 * kkc][1]);
        au[1] = cvtpk(p[2 * kkc][2],     p[2 * kkc][3]);
        au[2] = cvtpk(p[2 * kkc + 1][0], p[2 * kkc + 1][1]);
        au[3] = cvtpk(p[2 * kkc + 1][2], p[2 * kkc + 1][3]);
        short8_t ap = __builtin_bit_cast(short8_t, au);
        #pragma unroll
        for (int dc = 0; dc < 2; ++dc) {
            int vrow = dc * 16 + l15;
            short8_t bv = *(const short8_t*)(Vt + vrow * 64 + (((kkc * 4 + g) ^ (vrow & 7)) * 8));
            o2[dc] = __builtin_amdgcn_mfma_f32_16x16x32_bf16(ap, bv, o2[dc], 0, 0, 0);
        }
    }

    float irow[4];
    #pragma unroll
    for (int r = 0; r < 4; ++r) irow[r] = __shfl(inv, g * 4 + r);
    #pragma unroll
    for (int dc = 0; dc < 2; ++dc) {
        int d = dc * 16 + l15;
        if (d < 28) {
            #pragma unroll
            for (int r = 0; r < 4; ++r) {
                int row = q0 + w * 16 + g * 4 + r;
                catb[((size_t)b * N_ + row) * DIM_ + outoff + d] = bf16r(o2[dc][r] * irow[r]);
            }
        }
    }
}

// =====================================================================
extern "C" void kernel_launch(void* const* d_in, const int* in_sizes, int n_in,
                              void* d_out, int out_size, void* d_ws, size_t ws_size,
                              hipStream_t stream) {
    const float* x      = (const float*)d_in[0];
    const float* Wq     = (const float*)d_in[1];
    const float* Wkv_g  = (const float*)d_in[2];
    const float* sr_w   = (const float*)d_in[3];
    const float* sr_b   = (const float*)d_in[4];
    const float* ln_g   = (const float*)d_in[5];
    const float* ln_b   = (const float*)d_in[6];
    const float* lcg_w  = (const float*)d_in[7];
    const float* lcg_b  = (const float*)d_in[8];
    const float* kvl_dw = (const float*)d_in[9];
    const float* kvl_db = (const float*)d_in[10];
    const float* kvl_pw = (const float*)d_in[11];
    const float* kvl_pb = (const float*)d_in[12];
    const float* fc1_w  = (const float*)d_in[13];
    const float* sh1_w  = (const float*)d_in[14];
    const float* lc1_w  = (const float*)d_in[15];
    const float* lc1_b  = (const float*)d_in[16];
    const float* fc2_w  = (const float*)d_in[17];
    const float* sh2_w  = (const float*)d_in[18];
    const float* lc2_w  = (const float*)d_in[19];
    const float* lc2_b  = (const float*)d_in[20];
    const float* proj_w = (const float*)d_in[21];
    const float* proj_b = (const float*)d_in[22];
    float* out = (float*)d_out;
    char* base = (char*)d_ws;

    size_t o = 0;
    auto alloc = [&](size_t bytes) -> void* {
        void* p = base + o;
        o = (o + bytes + 255) & ~(size_t)255;
        return p;
    };
    ushort_t* q16   = (ushort_t*)alloc((size_t)B_ * N_ * DIM_ * 2);
    ushort_t* kvl16 = (ushort_t*)alloc((size_t)B_ * N_ * DL_ * 2);
    ushort_t* osp16 = (ushort_t*)alloc((size_t)NSPLIT * B_ * N_ * 64 * 2);
    float*    mls   = (float*)   alloc((size_t)NSPLIT * B_ * N_ * 2 * 4);
    ushort_t* xcat  = (ushort_t*)alloc((size_t)B_ * N_ * DIM_ * 2);  // xbf, then cat
    ushort_t* dwtb  = (ushort_t*)alloc((size_t)B_ * N_ * DL_ * 2);
    ushort_t* kgb   = (ushort_t*)alloc((size_t)B_ * NR_ * 64 * 2);
    float*    vg    = (float*)   alloc((size_t)B_ * NR_ * 64 * 4);
    ushort_t* vtb   = (ushort_t*)alloc((size_t)B_ * 64 * NR_ * 2);
    ushort_t* wqt   = (ushort_t*)alloc((size_t)512 * 512 * 2);
    ushort_t* pwt   = (ushort_t*)alloc((size_t)512 * 448 * 2);
    ushort_t* projt = (ushort_t*)alloc((size_t)512 * 512 * 2);
    float*    srwt  = (float*)   alloc((size_t)256 * 64 * 4);
    float*    kvm1  = (float*)   alloc((size_t)B_ * NH_ * 49 * HD_ * 4);
    float*    kvm2  = (float*)   alloc((size_t)B_ * NH_ * 49 * HD_ * 4);
    float*    kv1   = (float*)   alloc((size_t)B_ * NH_ * 49 * 56 * 4);
    float*    kv2   = (float*)   alloc((size_t)B_ * NH_ * 49 * 56 * 4);
    float*    v1c   = (float*)   alloc((size_t)B_ * NH_ * 49 * HD_ * 4);
    float*    v2c   = (float*)   alloc((size_t)B_ * NH_ * 49 * HD_ * 4);
    ushort_t* xbf   = xcat;
    ushort_t* catb  = xcat;

    const int M = B_ * N_;   // 25088

    // 1. merged prep
    prep_kernel<<<9280, 256, 0, stream>>>(Wq, kvl_pw, proj_w, sr_w, x,
                                          wqt, pwt, projt, srwt, xbf);

    // 2. fused: q-GEMM + dwt + srlnkv
    fused3_kernel<<<5096, 256, 0, stream>>>(xbf, wqt, q16,
                                            kvl_dw, kvl_db, dwtb,
                                            x, srwt, sr_b, ln_g, ln_b, Wkv_g,
                                            kgb, vg);

    // 3. fused: pointwise GEMM -> kvl16 + lcg/vtrans -> vtb
    fused2_kernel<<<882, 256, 0, stream>>>(dwtb, pwt, kvl_pb, kvl16,
                                           vg, lcg_w, lcg_b, vtb);

    // 4. fused: attn_global (split-K=4) + local_mean
    fused_ag_lm_kernel<<<2352, 512, 0, stream>>>(q16, kgb, vtb, osp16, mls,
                                                 kvl16, kvm1, kvm2);

    // 5. fc @ sh + v-conv (both branches, one launch)
    fcsh_vconv_kernel<<<32, 256, 0, stream>>>(kvm1, fc1_w, sh1_w, kv1,
                                              kvm2, fc2_w, sh2_w, kv2,
                                              lc1_w, lc1_b, v1c,
                                              lc2_w, lc2_b, v2c);

    // 6. fused: attn_local + combine (disjoint catb columns)
    fused_local_comb_kernel<<<12544, 256, 0, stream>>>(q16, kv1, v1c, kv2, v2c,
                                                       osp16, mls, catb);

    // 7. out = catb @ projt^T + proj_b
    gemm_bf16_kernel<true, false><<<dim3(M / 128, 4), 256, 0, stream>>>(
        catb, projt, proj_b, out, 512, 512, 512);
}